// Round 3
// baseline (582.821 us; speedup 1.0000x reference)
//
#include <hip/hip_runtime.h>

#define NBS    256
#define NELEC  64
#define NPART  80
#define NBASIS 32
#define KD     128
#define DD     128
#define IB     8     // i's per cfconv block

#define LOG2E 1.4426950408889634f
#define LN2   0.69314718055994530942f

typedef short v8s __attribute__((ext_vector_type(8)));
typedef float v4f __attribute__((ext_vector_type(4)));
typedef __bf16 bf2 __attribute__((ext_vector_type(2)));

#if __has_builtin(__builtin_amdgcn_exp2f)
#define EXP2F(x) __builtin_amdgcn_exp2f(x)
#else
#define EXP2F(x) __expf((x) * LN2)
#endif
#if __has_builtin(__builtin_amdgcn_logf)
#define LOG2F(x) __builtin_amdgcn_logf(x)
#else
#define LOG2F(x) __log2f(x)
#endif

// shifted softplus on a pre-scaled input: y = log2e * x
__device__ __forceinline__ float sspf2(float y) {
    float t = 1.0f + EXP2F(y);
    return __builtin_fmaf(LOG2F(t), LN2, -LN2);
}

__device__ __forceinline__ float bf2f(unsigned short u) {
    unsigned int x = ((unsigned int)u) << 16;
    return __builtin_bit_cast(float, x);
}
// native bf16 convert (RNE) — compiler selects v_cvt_pk_bf16_f32 on gfx950
__device__ __forceinline__ unsigned short f2bf(float f) {
    return __builtin_bit_cast(unsigned short, (__bf16)f);
}
__device__ __forceinline__ unsigned int pk2(float lo, float hi) {
    bf2 p;
    p.x = (__bf16)lo;
    p.y = (__bf16)hi;
    return __builtin_bit_cast(unsigned int, p);
}

// ---------------------------------------------------------------------------
// k_setup: ALL precompute in one wide dispatch.
// Flat index space regions:
//  R0 [0,2097152)        xs[b,i,:] = emb_elec[i,:]  (f32 master)
//  R1 [..,2621440)       zsbf[b, 64+j, k] = bf16(nuc[j,k])          (per b)
//  R2 [..,2670592)       kW2Tf A-frags (3 layers)
//  R3 [..,2682880)       kW1Tf A-frags (pre-scaled log2e)
//  R4 [..,2830336)       Wf B-frags (eiW/eoW1/eoW2 x 3; eoW1 scaled log2e)
//  R5 [..,2836480)       kb1f bias frags (scaled log2e)
//  R6 [..,2842624)       kb2f bias frags
//  R7 [..,2842880)       zs0 elec rows: 2 spin dots x 128 cols, bcast 32 rows
//  R8 [..,2844928)       zs0 nuc rows
// ---------------------------------------------------------------------------
__global__ __launch_bounds__(256) void k_setup(
    const float* __restrict__ emb_e, const float* __restrict__ nuc,
    const float* __restrict__ kW1g, const float* __restrict__ kW2g,
    const float* __restrict__ eiW, const float* __restrict__ eoW1,
    const float* __restrict__ eoW2,
    const float* __restrict__ kb1, const float* __restrict__ kb2,
    float* __restrict__ xs, unsigned short* __restrict__ zsbf,
    unsigned short* __restrict__ zs0,
    unsigned short* __restrict__ kW1Tf, unsigned short* __restrict__ kW2Tf,
    unsigned short* __restrict__ Wf,
    float* __restrict__ kb1f, float* __restrict__ kb2f) {
    int idx = blockIdx.x * 256 + threadIdx.x;
    if (idx < 2097152) {
        xs[idx] = emb_e[idx & (NELEC * DD - 1)];
    } else if (idx < 2621440) {
        int o = idx - 2097152;
        int b = o >> 11, rem = o & 2047;
        zsbf[(size_t)b * (NPART * KD) + NELEC * KD + rem] = f2bf(nuc[rem]);
    } else if (idx < 2670592) {
        int o = idx - 2621440;
        int l = o >> 14, oo = o & 16383;
        int mt = oo >> 11, ks = (oo >> 9) & 3, lane = (oo >> 3) & 63, jj = oo & 7;
        int q = lane >> 4, cc = lane & 15;
        kW2Tf[o] = f2bf(kW2g[(size_t)l * 16384 + (ks * 32 + q * 8 + jj) * 128 + mt * 16 + cc]);
    } else if (idx < 2682880) {
        int o = idx - 2670592;
        int l = o >> 12, oo = o & 4095;
        int kct = oo >> 9, lane = (oo >> 3) & 63, jj = oo & 7;
        int q = lane >> 4, cc = lane & 15;
        kW1Tf[o] = f2bf(kW1g[(size_t)l * 4096 + (q * 8 + jj) * 128 + kct * 16 + cc] * LOG2E);
    } else if (idx < 2830336) {
        int o = idx - 2682880;
        int bi = o >> 14, oo = o & 16383;
        int which = bi / 3, l = bi - which * 3;
        const float* src = (which == 0 ? eiW : which == 1 ? eoW1 : eoW2) + (size_t)l * 16384;
        float s = (which == 1) ? LOG2E : 1.0f;
        int mt = oo >> 11, ks = (oo >> 9) & 3, lane = (oo >> 3) & 63, jj = oo & 7;
        int q = lane >> 4, cc = lane & 15;
        Wf[o] = f2bf(src[(ks * 32 + q * 8 + jj) * 128 + mt * 16 + cc] * s);
    } else if (idx < 2836480) {
        int o = idx - 2830336;
        int l = o >> 11, rem = o & 2047;
        int w = rem >> 9, lane = (rem >> 3) & 63, e = o & 7;
        int mt = e >> 2, r = e & 3, q = lane >> 4;
        kb1f[o] = kb1[l * 128 + (2 * w + mt) * 16 + q * 4 + r] * LOG2E;
    } else if (idx < 2842624) {
        int o = idx - 2836480;
        int l = o >> 11, rem = o & 2047;
        int w = rem >> 9, lane = (rem >> 3) & 63, e = o & 7;
        int mt = e >> 2, r = e & 3, q = lane >> 4;
        kb2f[o] = kb2[l * 128 + (2 * w + mt) * 16 + q * 4 + r];
    } else if (idx < 2842880) {
        // zs0 elec: layer-0 zs is b-independent; emb has 2 distinct spin rows.
        int o = idx - 2842624;         // 0..255
        int s = o >> 7, k = o & 127;
        const float* e = emb_e + s * 32 * DD;   // representative row per spin
        float acc = 0.0f;
        for (int d = 0; d < 128; ++d)
            acc += bf2f(f2bf(e[d])) * bf2f(f2bf(eiW[d * 128 + k]));
        unsigned short v = f2bf(acc);
        for (int r = 0; r < 32; ++r)
            zs0[(s * 32 + r) * 128 + k] = v;
    } else if (idx < 2844928) {
        int o = idx - 2842880;         // 0..2047
        zs0[NELEC * KD + o] = f2bf(nuc[o]);
    }
}

// ---------------------------------------------------------------------------
// Fused tail per layer, split 2 blocks/b (rows independent):
//   h = ssp(agg@eoW1+b1); xs += h@eoW2+b2; (if !LAST) zs = xs@eiW[l+1].
// 256 threads = 4 waves: rt = w&1 (row-tile of 16), kh = w>>1 (kt half).
// ---------------------------------------------------------------------------
template <int LAST>
__global__ __launch_bounds__(256) void k_tail(
    const unsigned short* __restrict__ aggbf,
    const unsigned short* __restrict__ WfA,   // eoW1 frag (pre-scaled log2e)
    const float* __restrict__ b1,             // eob1 + l*128
    const unsigned short* __restrict__ WfB,   // eoW2 frag
    const float* __restrict__ b2,             // eob2 + l*128
    const unsigned short* __restrict__ WfC,   // eiW frag (l+1), unused if LAST
    float* __restrict__ xs,
    unsigned short* __restrict__ zsbf) {
    __shared__ float hl[32 * 129];
    const int blk = blockIdx.x;
    const int b = blk >> 1, row0 = (blk & 1) * 32;
    const int t = threadIdx.x, lane = t & 63, w = t >> 6;
    const int rt = w & 1, kh = w >> 1;
    const int q = lane >> 4, c = lane & 15;

    const unsigned short* ab = aggbf + (size_t)b * (NELEC * KD) + row0 * 128;
    v8s A[4];
#pragma unroll
    for (int ks = 0; ks < 4; ++ks)
        A[ks] = *(const v8s*)(ab + (rt * 16 + c) * 128 + ks * 32 + q * 8);

    // phase 1: h = ssp(agg @ eoW1 + b1) -> hl (f32)
#pragma unroll
    for (int kt2 = 0; kt2 < 4; ++kt2) {
        const int kt = kh * 4 + kt2;
        float bv = b1[kt * 16 + c] * LOG2E;
        v4f acc = {bv, bv, bv, bv};
#pragma unroll
        for (int ks = 0; ks < 4; ++ks) {
            v8s B = *(const v8s*)(WfA + (((size_t)kt * 4 + ks) * 64 + lane) * 8);
            acc = __builtin_amdgcn_mfma_f32_16x16x32_bf16(A[ks], B, acc, 0, 0, 0);
        }
#pragma unroll
        for (int r = 0; r < 4; ++r)
            hl[(rt * 16 + q * 4 + r) * 129 + kt * 16 + c] = sspf2(acc[r]);
    }
    __syncthreads();
#pragma unroll
    for (int ks = 0; ks < 4; ++ks) {
        const float* hp = hl + (rt * 16 + c) * 129 + ks * 32 + q * 8;
        uint4 u;
        u.x = pk2(hp[0], hp[1]);
        u.y = pk2(hp[2], hp[3]);
        u.z = pk2(hp[4], hp[5]);
        u.w = pk2(hp[6], hp[7]);
        A[ks] = __builtin_bit_cast(v8s, u);
    }
    __syncthreads();   // A2 reads done before phase-2 overwrites hl

    // phase 2: xs += h @ eoW2 + b2 (f32 master); stash xs_new in hl
    float* xb = xs + (size_t)b * (NELEC * DD) + row0 * 128;
#pragma unroll
    for (int kt2 = 0; kt2 < 4; ++kt2) {
        const int kt = kh * 4 + kt2;
        float bv = b2[kt * 16 + c];
        v4f acc = {bv, bv, bv, bv};
#pragma unroll
        for (int ks = 0; ks < 4; ++ks) {
            v8s B = *(const v8s*)(WfB + (((size_t)kt * 4 + ks) * 64 + lane) * 8);
            acc = __builtin_amdgcn_mfma_f32_16x16x32_bf16(A[ks], B, acc, 0, 0, 0);
        }
#pragma unroll
        for (int r = 0; r < 4; ++r) {
            int row = rt * 16 + q * 4 + r, col = kt * 16 + c;
            float nv = xb[row * 128 + col] + acc[r];
            xb[row * 128 + col] = nv;
            if (!LAST) hl[row * 129 + col] = nv;
        }
    }
    if (!LAST) {
        __syncthreads();
#pragma unroll
        for (int ks = 0; ks < 4; ++ks) {
            const float* hp = hl + (rt * 16 + c) * 129 + ks * 32 + q * 8;
            uint4 u;
            u.x = pk2(hp[0], hp[1]);
            u.y = pk2(hp[2], hp[3]);
            u.z = pk2(hp[4], hp[5]);
            u.w = pk2(hp[6], hp[7]);
            A[ks] = __builtin_bit_cast(v8s, u);
        }
        unsigned short* zb = zsbf + (size_t)b * (NPART * KD) + row0 * 128;
#pragma unroll
        for (int kt2 = 0; kt2 < 4; ++kt2) {
            const int kt = kh * 4 + kt2;
            v4f acc = {0.0f, 0.0f, 0.0f, 0.0f};
#pragma unroll
            for (int ks = 0; ks < 4; ++ks) {
                v8s B = *(const v8s*)(WfC + (((size_t)kt * 4 + ks) * 64 + lane) * 8);
                acc = __builtin_amdgcn_mfma_f32_16x16x32_bf16(A[ks], B, acc, 0, 0, 0);
            }
#pragma unroll
            for (int r = 0; r < 4; ++r)
                zb[(rt * 16 + q * 4 + r) * 128 + kt * 16 + c] = f2bf(acc[r]);
        }
    }
}

// ---------------------------------------------------------------------------
// cfconv: ONE barrier per i via double-buffered LDS.
// Per ii: [issue dists(ii+1) loads] GEMM1(ii)->s_X1[p]; stage dists(ii+1)->
// s_dists[p^1]; barrier; GEMM2(ii) + masked reduce + agg write.
// Hazards: every buffer's write is >=1 barrier after its last read (dbuf).
// zf loaded per-ii post-barrier (anti-LICM asm) to cut steady VGPR pressure.
// ---------------------------------------------------------------------------
__global__ __launch_bounds__(256, 2) void k_cfconv_mfma(
    const float* __restrict__ dists,
    const float* __restrict__ kb1f, const float* __restrict__ kb2f,
    const unsigned short* __restrict__ zs, int zstride,
    const unsigned short* __restrict__ kW1Tf,
    const unsigned short* __restrict__ kW2Tf,
    unsigned short* __restrict__ aggbf, int l) {
    __shared__ __align__(16) unsigned short s_dists[2][2560];  // [jt(5)][lane][8]
    __shared__ __align__(16) unsigned short s_X1[2][10240];    // [jt(5)][ks(4)][lane][8]

    const int blk = blockIdx.x;
    const int b = blk >> 3;
    const int ig = blk & 7;
    const int t = threadIdx.x;
    const int lane = t & 63;
    const int w = t >> 6;
    const int q = lane >> 4;
    const int c = lane & 15;

    // --- per-block prelude: weights + biases (amortized over IB i's) ---
    v8s a1[2], a2[2][4];
    {
        const uint4* w1p = (const uint4*)kW1Tf;
        const uint4* w2p = (const uint4*)kW2Tf;
#pragma unroll
        for (int t1 = 0; t1 < 2; ++t1) {
            uint4 u = w1p[(l * 8 + 2 * w + t1) * 64 + lane];
            a1[t1] = __builtin_bit_cast(v8s, u);
        }
#pragma unroll
        for (int mt = 0; mt < 2; ++mt)
#pragma unroll
            for (int ks = 0; ks < 4; ++ks) {
                uint4 u = w2p[((l * 8 + 2 * w + mt) * 4 + ks) * 64 + lane];
                a2[mt][ks] = __builtin_bit_cast(v8s, u);
            }
    }
    float4 kb1v[2], kb2v[2];
    {
        const float4* p1 = (const float4*)(kb1f + ((size_t)(l * 4 + w) * 64 + lane) * 8);
        kb1v[0] = p1[0];
        kb1v[1] = p1[1];
        const float4* p2 = (const float4*)(kb2f + ((size_t)(l * 4 + w) * 64 + lane) * 8);
        kb2v[0] = p2[0];
        kb2v[1] = p2[1];
    }
    const unsigned short* zbase = zs + (size_t)b * zstride + w * 32 + q * 4;
    const float* dbase = dists + ((size_t)b * NELEC + ig * IB) * (NPART * NBASIS);

    float4 p0a, p0b, p1a, p1b;
    auto LOADD = [&](int ix) {
        const float* dg = dbase + (size_t)ix * (NPART * NBASIS);
        const float* dj = dg + (w * 16 + c) * 32 + q * 8;
        p0a = *(const float4*)dj;
        p0b = *(const float4*)(dj + 4);
        if (w == 0) {
            const float* dj4 = dg + (64 + c) * 32 + q * 8;
            p1a = *(const float4*)dj4;
            p1b = *(const float4*)(dj4 + 4);
        }
    };
    auto STORED = [&](unsigned short* sd) {
        uint4 pk;
        pk.x = pk2(p0a.x, p0a.y); pk.y = pk2(p0a.z, p0a.w);
        pk.z = pk2(p0b.x, p0b.y); pk.w = pk2(p0b.z, p0b.w);
        *(uint4*)(sd + (w * 64 + lane) * 8) = pk;
        if (w == 0) {
            uint4 pk4;
            pk4.x = pk2(p1a.x, p1a.y); pk4.y = pk2(p1a.z, p1a.w);
            pk4.z = pk2(p1b.x, p1b.y); pk4.w = pk2(p1b.z, p1b.w);
            *(uint4*)(sd + (4 * 64 + lane) * 8) = pk4;
        }
    };

    // prologue: stage dists(0)
    LOADD(0);
    STORED(s_dists[0]);
    __syncthreads();

#pragma unroll 2
    for (int ii = 0; ii < IB; ++ii) {
        const int p = ii & 1;
        const int i = ig * IB + ii;

        // T14: issue next-i dists loads (waited at STORED below)
        if (ii + 1 < IB) LOADD(ii + 1);

        // GEMM1-T: 10 MFMA, ssp, write X1 B-frags into s_X1[p]
#pragma unroll
        for (int jt = 0; jt < 5; ++jt) {
            v8s bd = *(const v8s*)(&s_dists[p][(jt * 64 + lane) * 8]);
#pragma unroll
            for (int t1 = 0; t1 < 2; ++t1) {
                v4f d = {kb1v[t1].x, kb1v[t1].y, kb1v[t1].z, kb1v[t1].w};
                d = __builtin_amdgcn_mfma_f32_16x16x32_bf16(a1[t1], bd, d, 0, 0, 0);
                uint2 o;
                o.x = pk2(sspf2(d[0]), sspf2(d[1]));
                o.y = pk2(sspf2(d[2]), sspf2(d[3]));
                int qB = 2 * t1 + (q >> 1);
                *(uint2*)(&s_X1[p][((jt * 4 + w) * 64 + qB * 16 + c) * 8 + (q & 1) * 4]) = o;
            }
        }

        // stage dists(ii+1) into the other buffer (pre-barrier; read next iter)
        if (ii + 1 < IB) STORED(s_dists[p ^ 1]);

        __syncthreads();   // the ONLY barrier per ii

        // per-ii zf load (anti-LICM: opaque pointer), hidden under GEMM2 MFMAs
        const unsigned short* zb = zbase;
        asm volatile("" : "+v"(zb));
        float zf[2][5][4];
#pragma unroll
        for (int mt = 0; mt < 2; ++mt)
#pragma unroll
            for (int jt = 0; jt < 5; ++jt) {
                ushort4 zv = *(const ushort4*)(zb + (jt * 16 + c) * 128 + mt * 16);
                zf[mt][jt][0] = bf2f(zv.x);
                zf[mt][jt][1] = bf2f(zv.y);
                zf[mt][jt][2] = bf2f(zv.z);
                zf[mt][jt][3] = bf2f(zv.w);
            }

        // GEMM2-T: 40 MFMA over (2 mt, 5 jt, 4 ks), full K sum per wave
        v4f acc[2][5];
#pragma unroll
        for (int mt = 0; mt < 2; ++mt)
#pragma unroll
            for (int jt = 0; jt < 5; ++jt)
                acc[mt][jt] = (v4f){(&kb2v[mt].x)[0], (&kb2v[mt].x)[1],
                                    (&kb2v[mt].x)[2], (&kb2v[mt].x)[3]};
#pragma unroll
        for (int jt = 0; jt < 5; ++jt) {
#pragma unroll
            for (int ks = 0; ks < 4; ++ks) {
                v8s bx = *(const v8s*)(&s_X1[p][((jt * 4 + ks) * 64 + lane) * 8]);
                acc[0][jt] = __builtin_amdgcn_mfma_f32_16x16x32_bf16(a2[0][ks], bx, acc[0][jt], 0, 0, 0);
                acc[1][jt] = __builtin_amdgcn_mfma_f32_16x16x32_bf16(a2[1][ks], bx, acc[1][jt], 0, 0, 0);
            }
        }

        // weighted reduce over j, diagonal j==i masked (uniform-branched)
        float red[8];
#pragma unroll
        for (int v = 0; v < 8; ++v) red[v] = 0.0f;
        const int jt_i = i >> 4;
        const bool lanehit = (c == (i & 15));
#pragma unroll
        for (int jt = 0; jt < 5; ++jt) {
            if (jt == jt_i) {
#pragma unroll
                for (int mt = 0; mt < 2; ++mt)
#pragma unroll
                    for (int r = 0; r < 4; ++r) {
                        float a = lanehit ? 0.0f : acc[mt][jt][r];
                        red[mt * 4 + r] += a * zf[mt][jt][r];
                    }
            } else {
#pragma unroll
                for (int mt = 0; mt < 2; ++mt)
#pragma unroll
                    for (int r = 0; r < 4; ++r)
                        red[mt * 4 + r] += acc[mt][jt][r] * zf[mt][jt][r];
            }
        }

        // butterfly reduce over the 16 j-lanes
        float vals[8];
#pragma unroll
        for (int v = 0; v < 8; ++v) vals[v] = red[v];
#pragma unroll
        for (int B = 0; B < 3; ++B) {
            const int off = 1 << B;
            const bool up = (c >> B) & 1;
#pragma unroll
            for (int k2 = 0; k2 < (4 >> B); ++k2) {
                float aa = vals[2 * k2], bb = vals[2 * k2 + 1];
                float mine = up ? bb : aa;
                float other = up ? aa : bb;
                vals[k2] = mine + __shfl_xor(other, off, 64);
            }
        }
        float x = vals[0] + __shfl_xor(vals[0], 8, 64);

        if (c < 8) {
            int kcol = w * 32 + ((c >> 2) & 1) * 16 + q * 4 + (c & 3);
            aggbf[((size_t)b * NELEC + i) * 128 + kcol] = f2bf(x);
        }
    }
}

extern "C" void kernel_launch(void* const* d_in, const int* in_sizes, int n_in,
                              void* d_out, int out_size, void* d_ws, size_t ws_size,
                              hipStream_t stream) {
    const float* dists = (const float*)d_in[0];
    const float* emb_e = (const float*)d_in[1];
    const float* emb_n = (const float*)d_in[2];
    const float* kW1   = (const float*)d_in[3];
    const float* kb1   = (const float*)d_in[4];
    const float* kW2   = (const float*)d_in[5];
    const float* kb2   = (const float*)d_in[6];
    const float* eiW   = (const float*)d_in[7];
    const float* eoW1  = (const float*)d_in[8];
    const float* eob1  = (const float*)d_in[9];
    const float* eoW2  = (const float*)d_in[10];
    const float* eob2  = (const float*)d_in[11];

    float* xs = (float*)d_out;                                  // (256,64,128) f32
    unsigned short* zsbf  = (unsigned short*)d_ws;              // (256,80,128) bf16
    unsigned short* aggbf = zsbf + NBS * NPART * KD;            // (256,64,128) bf16
    unsigned short* zs0   = aggbf + NBS * NELEC * KD;           // (80,128) bf16
    unsigned short* kW1Tf = zs0 + NPART * KD;                   // 3*4096
    unsigned short* kW2Tf = kW1Tf + 3 * 4096;                   // 3*16384
    unsigned short* Wf    = kW2Tf + 3 * 16384;                  // 9*16384
    float* kb1f = (float*)(Wf + 9 * 16384);                     // 6144 f32
    float* kb2f = kb1f + 3 * 4 * 64 * 8;                        // 6144 f32

    k_setup<<<11113, 256, 0, stream>>>(emb_e, emb_n, kW1, kW2, eiW, eoW1, eoW2,
                                       kb1, kb2, xs, zsbf, zs0,
                                       kW1Tf, kW2Tf, Wf, kb1f, kb2f);

    for (int l = 0; l < 3; ++l) {
        k_cfconv_mfma<<<NBS * (NELEC / IB), 256, 0, stream>>>(
            dists, kb1f, kb2f,
            l == 0 ? zs0 : zsbf, l == 0 ? 0 : NPART * KD,
            kW1Tf, kW2Tf, aggbf, l);

        if (l < 2) {
            k_tail<0><<<NBS * 2, 256, 0, stream>>>(
                aggbf,
                Wf + (size_t)(1 * 3 + l) * 16384, eob1 + l * DD,
                Wf + (size_t)(2 * 3 + l) * 16384, eob2 + l * DD,
                Wf + (size_t)(0 * 3 + (l + 1)) * 16384,
                xs, zsbf);
        } else {
            k_tail<1><<<NBS * 2, 256, 0, stream>>>(
                aggbf,
                Wf + (size_t)(1 * 3 + l) * 16384, eob1 + l * DD,
                Wf + (size_t)(2 * 3 + l) * 16384, eob2 + l * DD,
                nullptr,
                xs, zsbf);
        }
    }
}

// Round 4
// 455.607 us; speedup vs baseline: 1.2792x; 1.2792x over previous
//
#include <hip/hip_runtime.h>

#define NBS    256
#define NELEC  64
#define NPART  80
#define NBASIS 32
#define KD     128
#define DD     128
#define IB     8     // i's per cfconv block

#define LOG2E 1.4426950408889634f
#define LN2   0.69314718055994530942f

typedef short v8s __attribute__((ext_vector_type(8)));
typedef float v4f __attribute__((ext_vector_type(4)));
typedef __bf16 bf2 __attribute__((ext_vector_type(2)));

#if __has_builtin(__builtin_amdgcn_exp2f)
#define EXP2F(x) __builtin_amdgcn_exp2f(x)
#else
#define EXP2F(x) __expf((x) * LN2)
#endif
#if __has_builtin(__builtin_amdgcn_logf)
#define LOG2F(x) __builtin_amdgcn_logf(x)
#else
#define LOG2F(x) __log2f(x)
#endif

// shifted softplus on a pre-scaled input: y = log2e * x
__device__ __forceinline__ float sspf2(float y) {
    float t = 1.0f + EXP2F(y);
    return __builtin_fmaf(LOG2F(t), LN2, -LN2);
}

__device__ __forceinline__ float bf2f(unsigned short u) {
    unsigned int x = ((unsigned int)u) << 16;
    return __builtin_bit_cast(float, x);
}
// native bf16 convert (RNE) — compiler selects v_cvt_pk_bf16_f32 on gfx950
__device__ __forceinline__ unsigned short f2bf(float f) {
    return __builtin_bit_cast(unsigned short, (__bf16)f);
}
__device__ __forceinline__ unsigned int pk2(float lo, float hi) {
    bf2 p;
    p.x = (__bf16)lo;
    p.y = (__bf16)hi;
    return __builtin_bit_cast(unsigned int, p);
}

// ---------------------------------------------------------------------------
// k_setup: ALL precompute in one wide dispatch.
// Flat index space regions:
//  R0 [0,2097152)        xs[b,i,:] = emb_elec[i,:]  (f32 master)
//  R1 [..,2621440)       zsbf[b, 64+j, k] = bf16(nuc[j,k])          (per b)
//  R2 [..,2670592)       kW2Tf A-frags (3 layers)
//  R3 [..,2682880)       kW1Tf A-frags (pre-scaled log2e)
//  R4 [..,2830336)       Wf B-frags (eiW/eoW1/eoW2 x 3; eoW1 scaled log2e)
//  R5 [..,2836480)       kb1f bias frags (scaled log2e)
//  R6 [..,2842624)       kb2f bias frags
//  R7 [..,2844672)       zs0 elec: 8 lanes per (spin,k) dot + shuffle reduce
//  R8 [..,2846720)       zs0 nuc rows
// ---------------------------------------------------------------------------
__global__ __launch_bounds__(256) void k_setup(
    const float* __restrict__ emb_e, const float* __restrict__ nuc,
    const float* __restrict__ kW1g, const float* __restrict__ kW2g,
    const float* __restrict__ eiW, const float* __restrict__ eoW1,
    const float* __restrict__ eoW2,
    const float* __restrict__ kb1, const float* __restrict__ kb2,
    float* __restrict__ xs, unsigned short* __restrict__ zsbf,
    unsigned short* __restrict__ zs0,
    unsigned short* __restrict__ kW1Tf, unsigned short* __restrict__ kW2Tf,
    unsigned short* __restrict__ Wf,
    float* __restrict__ kb1f, float* __restrict__ kb2f) {
    int idx = blockIdx.x * 256 + threadIdx.x;
    if (idx < 2097152) {
        xs[idx] = emb_e[idx & (NELEC * DD - 1)];
    } else if (idx < 2621440) {
        int o = idx - 2097152;
        int b = o >> 11, rem = o & 2047;
        zsbf[(size_t)b * (NPART * KD) + NELEC * KD + rem] = f2bf(nuc[rem]);
    } else if (idx < 2670592) {
        int o = idx - 2621440;
        int l = o >> 14, oo = o & 16383;
        int mt = oo >> 11, ks = (oo >> 9) & 3, lane = (oo >> 3) & 63, jj = oo & 7;
        int q = lane >> 4, cc = lane & 15;
        kW2Tf[o] = f2bf(kW2g[(size_t)l * 16384 + (ks * 32 + q * 8 + jj) * 128 + mt * 16 + cc]);
    } else if (idx < 2682880) {
        int o = idx - 2670592;
        int l = o >> 12, oo = o & 4095;
        int kct = oo >> 9, lane = (oo >> 3) & 63, jj = oo & 7;
        int q = lane >> 4, cc = lane & 15;
        kW1Tf[o] = f2bf(kW1g[(size_t)l * 4096 + (q * 8 + jj) * 128 + kct * 16 + cc] * LOG2E);
    } else if (idx < 2830336) {
        int o = idx - 2682880;
        int bi = o >> 14, oo = o & 16383;
        int which = bi / 3, l = bi - which * 3;
        const float* src = (which == 0 ? eiW : which == 1 ? eoW1 : eoW2) + (size_t)l * 16384;
        float s = (which == 1) ? LOG2E : 1.0f;
        int mt = oo >> 11, ks = (oo >> 9) & 3, lane = (oo >> 3) & 63, jj = oo & 7;
        int q = lane >> 4, cc = lane & 15;
        Wf[o] = f2bf(src[(ks * 32 + q * 8 + jj) * 128 + mt * 16 + cc] * s);
    } else if (idx < 2836480) {
        int o = idx - 2830336;
        int l = o >> 11, rem = o & 2047;
        int w = rem >> 9, lane = (rem >> 3) & 63, e = o & 7;
        int mt = e >> 2, r = e & 3, q = lane >> 4;
        kb1f[o] = kb1[l * 128 + (2 * w + mt) * 16 + q * 4 + r] * LOG2E;
    } else if (idx < 2842624) {
        int o = idx - 2836480;
        int l = o >> 11, rem = o & 2047;
        int w = rem >> 9, lane = (rem >> 3) & 63, e = o & 7;
        int mt = e >> 2, r = e & 3, q = lane >> 4;
        kb2f[o] = kb2[l * 128 + (2 * w + mt) * 16 + q * 4 + r];
    } else if (idx < 2844672) {
        // zs0 elec: layer-0 zs is b-independent (2 distinct spin rows).
        // 8 lanes per (s,k): each sums 16 d's, 3-step shuffle reduce.
        int o = idx - 2842624;          // 0..2047, region block-aligned
        int s = o >> 10, rem = o & 1023;
        int k = rem >> 3, part = o & 7;
        const float* e = emb_e + s * 32 * DD;
        float partial = 0.0f;
        for (int d = part * 16; d < part * 16 + 16; ++d)
            partial += bf2f(f2bf(e[d])) * bf2f(f2bf(eiW[d * 128 + k]));
        partial += __shfl_xor(partial, 1, 64);
        partial += __shfl_xor(partial, 2, 64);
        partial += __shfl_xor(partial, 4, 64);
        if (part == 0) {
            unsigned short v = f2bf(partial);
            for (int r = 0; r < 32; ++r)
                zs0[(s * 32 + r) * 128 + k] = v;
        }
    } else if (idx < 2846720) {
        int o = idx - 2844672;          // 0..2047
        zs0[NELEC * KD + o] = f2bf(nuc[o]);
    }
}

// ---------------------------------------------------------------------------
// Fused tail per layer, split 2 blocks/b (rows independent):
//   h = ssp(agg@eoW1+b1); xs += h@eoW2+b2; (if !LAST) zs = xs@eiW[l+1].
// ---------------------------------------------------------------------------
template <int LAST>
__global__ __launch_bounds__(256) void k_tail(
    const unsigned short* __restrict__ aggbf,
    const unsigned short* __restrict__ WfA,   // eoW1 frag (pre-scaled log2e)
    const float* __restrict__ b1,             // eob1 + l*128
    const unsigned short* __restrict__ WfB,   // eoW2 frag
    const float* __restrict__ b2,             // eob2 + l*128
    const unsigned short* __restrict__ WfC,   // eiW frag (l+1), unused if LAST
    float* __restrict__ xs,
    unsigned short* __restrict__ zsbf) {
    __shared__ float hl[32 * 129];
    const int blk = blockIdx.x;
    const int b = blk >> 1, row0 = (blk & 1) * 32;
    const int t = threadIdx.x, lane = t & 63, w = t >> 6;
    const int rt = w & 1, kh = w >> 1;
    const int q = lane >> 4, c = lane & 15;

    const unsigned short* ab = aggbf + (size_t)b * (NELEC * KD) + row0 * 128;
    v8s A[4];
#pragma unroll
    for (int ks = 0; ks < 4; ++ks)
        A[ks] = *(const v8s*)(ab + (rt * 16 + c) * 128 + ks * 32 + q * 8);

    // phase 1: h = ssp(agg @ eoW1 + b1) -> hl (f32)
#pragma unroll
    for (int kt2 = 0; kt2 < 4; ++kt2) {
        const int kt = kh * 4 + kt2;
        float bv = b1[kt * 16 + c] * LOG2E;
        v4f acc = {bv, bv, bv, bv};
#pragma unroll
        for (int ks = 0; ks < 4; ++ks) {
            v8s B = *(const v8s*)(WfA + (((size_t)kt * 4 + ks) * 64 + lane) * 8);
            acc = __builtin_amdgcn_mfma_f32_16x16x32_bf16(A[ks], B, acc, 0, 0, 0);
        }
#pragma unroll
        for (int r = 0; r < 4; ++r)
            hl[(rt * 16 + q * 4 + r) * 129 + kt * 16 + c] = sspf2(acc[r]);
    }
    __syncthreads();
#pragma unroll
    for (int ks = 0; ks < 4; ++ks) {
        const float* hp = hl + (rt * 16 + c) * 129 + ks * 32 + q * 8;
        uint4 u;
        u.x = pk2(hp[0], hp[1]);
        u.y = pk2(hp[2], hp[3]);
        u.z = pk2(hp[4], hp[5]);
        u.w = pk2(hp[6], hp[7]);
        A[ks] = __builtin_bit_cast(v8s, u);
    }
    __syncthreads();   // A2 reads done before phase-2 overwrites hl

    // phase 2: xs += h @ eoW2 + b2 (f32 master); stash xs_new in hl
    float* xb = xs + (size_t)b * (NELEC * DD) + row0 * 128;
#pragma unroll
    for (int kt2 = 0; kt2 < 4; ++kt2) {
        const int kt = kh * 4 + kt2;
        float bv = b2[kt * 16 + c];
        v4f acc = {bv, bv, bv, bv};
#pragma unroll
        for (int ks = 0; ks < 4; ++ks) {
            v8s B = *(const v8s*)(WfB + (((size_t)kt * 4 + ks) * 64 + lane) * 8);
            acc = __builtin_amdgcn_mfma_f32_16x16x32_bf16(A[ks], B, acc, 0, 0, 0);
        }
#pragma unroll
        for (int r = 0; r < 4; ++r) {
            int row = rt * 16 + q * 4 + r, col = kt * 16 + c;
            float nv = xb[row * 128 + col] + acc[r];
            xb[row * 128 + col] = nv;
            if (!LAST) hl[row * 129 + col] = nv;
        }
    }
    if (!LAST) {
        __syncthreads();
#pragma unroll
        for (int ks = 0; ks < 4; ++ks) {
            const float* hp = hl + (rt * 16 + c) * 129 + ks * 32 + q * 8;
            uint4 u;
            u.x = pk2(hp[0], hp[1]);
            u.y = pk2(hp[2], hp[3]);
            u.z = pk2(hp[4], hp[5]);
            u.w = pk2(hp[6], hp[7]);
            A[ks] = __builtin_bit_cast(v8s, u);
        }
        unsigned short* zb = zsbf + (size_t)b * (NPART * KD) + row0 * 128;
#pragma unroll
        for (int kt2 = 0; kt2 < 4; ++kt2) {
            const int kt = kh * 4 + kt2;
            v4f acc = {0.0f, 0.0f, 0.0f, 0.0f};
#pragma unroll
            for (int ks = 0; ks < 4; ++ks) {
                v8s B = *(const v8s*)(WfC + (((size_t)kt * 4 + ks) * 64 + lane) * 8);
                acc = __builtin_amdgcn_mfma_f32_16x16x32_bf16(A[ks], B, acc, 0, 0, 0);
            }
#pragma unroll
            for (int r = 0; r < 4; ++r)
                zb[(rt * 16 + q * 4 + r) * 128 + kt * 16 + c] = f2bf(acc[r]);
        }
    }
}

// ---------------------------------------------------------------------------
// cfconv: r2-proven structure (single-buffer LDS, two barriers per ii,
// zf in prelude, T14 prefetch). New: launch_bounds(256,3) + per-jt
// accumulator retirement in GEMM2 (acc live = 8 regs, not 40) so peak
// register use fits 3 waves/SIMD (512/3 = 170).
// ---------------------------------------------------------------------------
__global__ __launch_bounds__(256, 3) void k_cfconv_mfma(
    const float* __restrict__ dists,
    const float* __restrict__ kb1f, const float* __restrict__ kb2f,
    const unsigned short* __restrict__ zs, int zstride,
    const unsigned short* __restrict__ kW1Tf,
    const unsigned short* __restrict__ kW2Tf,
    unsigned short* __restrict__ aggbf, int l) {
    __shared__ __align__(16) unsigned short s_dists[2560];   // [jt(5)][lane(64)][jj(8)]
    __shared__ __align__(16) unsigned short s_X1[10240];     // [jt(5)][ks(4)][lane(64)][jj(8)]

    const int blk = blockIdx.x;
    const int b = blk >> 3;
    const int ig = blk & 7;
    const int t = threadIdx.x;
    const int lane = t & 63;
    const int w = t >> 6;
    const int q = lane >> 4;
    const int c = lane & 15;

    // --- per-block prelude: weights, biases, zs (amortized over IB i's) ---
    v8s a1[2], a2[2][4];
    {
        const uint4* w1p = (const uint4*)kW1Tf;
        const uint4* w2p = (const uint4*)kW2Tf;
#pragma unroll
        for (int t1 = 0; t1 < 2; ++t1) {
            uint4 u = w1p[(l * 8 + 2 * w + t1) * 64 + lane];
            a1[t1] = __builtin_bit_cast(v8s, u);
        }
#pragma unroll
        for (int mt = 0; mt < 2; ++mt)
#pragma unroll
            for (int ks = 0; ks < 4; ++ks) {
                uint4 u = w2p[((l * 8 + 2 * w + mt) * 4 + ks) * 64 + lane];
                a2[mt][ks] = __builtin_bit_cast(v8s, u);
            }
    }
    float4 kb1v[2], kb2v[2];
    {
        const float4* p1 = (const float4*)(kb1f + ((size_t)(l * 4 + w) * 64 + lane) * 8);
        kb1v[0] = p1[0];
        kb1v[1] = p1[1];
        const float4* p2 = (const float4*)(kb2f + ((size_t)(l * 4 + w) * 64 + lane) * 8);
        kb2v[0] = p2[0];
        kb2v[1] = p2[1];
    }
    // zs values at this lane's reduce positions: row j=jt*16+c, col w*32+mt*16+q*4+r
    float zf[2][5][4];
    {
        const unsigned short* zb = zs + (size_t)b * zstride + w * 32 + q * 4;
#pragma unroll
        for (int mt = 0; mt < 2; ++mt)
#pragma unroll
            for (int jt = 0; jt < 5; ++jt) {
                ushort4 zv = *(const ushort4*)(zb + (jt * 16 + c) * 128 + mt * 16);
                zf[mt][jt][0] = bf2f(zv.x);
                zf[mt][jt][1] = bf2f(zv.y);
                zf[mt][jt][2] = bf2f(zv.z);
                zf[mt][jt][3] = bf2f(zv.w);
            }
    }

    const float* dbase = dists + ((size_t)b * NELEC + ig * IB) * (NPART * NBASIS);

    float4 p0a, p0b, p1a, p1b;
    auto LOADD = [&](int ix) {
        const float* dg = dbase + (size_t)ix * (NPART * NBASIS);
        const float* dj = dg + (w * 16 + c) * 32 + q * 8;
        p0a = *(const float4*)dj;
        p0b = *(const float4*)(dj + 4);
        if (w == 0) {
            const float* dj4 = dg + (64 + c) * 32 + q * 8;
            p1a = *(const float4*)dj4;
            p1b = *(const float4*)(dj4 + 4);
        }
    };
    auto STORED = [&]() {
        uint4 pk;
        pk.x = pk2(p0a.x, p0a.y); pk.y = pk2(p0a.z, p0a.w);
        pk.z = pk2(p0b.x, p0b.y); pk.w = pk2(p0b.z, p0b.w);
        *(uint4*)(s_dists + (w * 64 + lane) * 8) = pk;
        if (w == 0) {
            uint4 pk4;
            pk4.x = pk2(p1a.x, p1a.y); pk4.y = pk2(p1a.z, p1a.w);
            pk4.z = pk2(p1b.x, p1b.y); pk4.w = pk2(p1b.z, p1b.w);
            *(uint4*)(s_dists + (4 * 64 + lane) * 8) = pk4;
        }
    };

    // prologue: stage dists(0)
    LOADD(0);
    STORED();

#pragma unroll 1
    for (int ii = 0; ii < IB; ++ii) {
        const int i = ig * IB + ii;
        __syncthreads();    // s_dists(ii) visible

        // T14: issue next-i dists loads (waited at STORED below)
        if (ii + 1 < IB) LOADD(ii + 1);

        // GEMM1-T: 10 MFMA, ssp, write X1 B-frags
#pragma unroll
        for (int jt = 0; jt < 5; ++jt) {
            v8s bd = *(const v8s*)(s_dists + (jt * 64 + lane) * 8);
#pragma unroll
            for (int t1 = 0; t1 < 2; ++t1) {
                v4f d = {kb1v[t1].x, kb1v[t1].y, kb1v[t1].z, kb1v[t1].w};
                d = __builtin_amdgcn_mfma_f32_16x16x32_bf16(a1[t1], bd, d, 0, 0, 0);
                uint2 o;
                o.x = pk2(sspf2(d[0]), sspf2(d[1]));
                o.y = pk2(sspf2(d[2]), sspf2(d[3]));
                int qB = 2 * t1 + (q >> 1);
                *(uint2*)(s_X1 + ((jt * 4 + w) * 64 + qB * 16 + c) * 8 + (q & 1) * 4) = o;
            }
        }
        __syncthreads();    // X1 visible; s_dists(ii) reads all done

        // stage dists(ii+1) (safe: all reads of s_dists(ii) pre-barrier)
        if (ii + 1 < IB) STORED();

        // GEMM2-T with per-jt retirement: acc live = 2 v4f, not 2x5.
        float red[8];
#pragma unroll
        for (int v = 0; v < 8; ++v) red[v] = 0.0f;
        const int jt_i = i >> 4;
        const bool lanehit = (c == (i & 15));
#pragma unroll
        for (int jt = 0; jt < 5; ++jt) {
            v4f acc0 = {kb2v[0].x, kb2v[0].y, kb2v[0].z, kb2v[0].w};
            v4f acc1 = {kb2v[1].x, kb2v[1].y, kb2v[1].z, kb2v[1].w};
#pragma unroll
            for (int ks = 0; ks < 4; ++ks) {
                v8s bx = *(const v8s*)(s_X1 + ((jt * 4 + ks) * 64 + lane) * 8);
                acc0 = __builtin_amdgcn_mfma_f32_16x16x32_bf16(a2[0][ks], bx, acc0, 0, 0, 0);
                acc1 = __builtin_amdgcn_mfma_f32_16x16x32_bf16(a2[1][ks], bx, acc1, 0, 0, 0);
            }
            if (jt == jt_i) {   // wave-uniform branch; per-lane mask only here
#pragma unroll
                for (int r = 0; r < 4; ++r) {
                    float a0 = lanehit ? 0.0f : acc0[r];
                    float a1v = lanehit ? 0.0f : acc1[r];
                    red[r]     += a0 * zf[0][jt][r];
                    red[4 + r] += a1v * zf[1][jt][r];
                }
            } else {
#pragma unroll
                for (int r = 0; r < 4; ++r) {
                    red[r]     += acc0[r] * zf[0][jt][r];
                    red[4 + r] += acc1[r] * zf[1][jt][r];
                }
            }
        }

        // butterfly reduce over the 16 j-lanes
        float vals[8];
#pragma unroll
        for (int v = 0; v < 8; ++v) vals[v] = red[v];
#pragma unroll
        for (int B = 0; B < 3; ++B) {
            const int off = 1 << B;
            const bool up = (c >> B) & 1;
#pragma unroll
            for (int k2 = 0; k2 < (4 >> B); ++k2) {
                float aa = vals[2 * k2], bb = vals[2 * k2 + 1];
                float mine = up ? bb : aa;
                float other = up ? aa : bb;
                vals[k2] = mine + __shfl_xor(other, off, 64);
            }
        }
        float x = vals[0] + __shfl_xor(vals[0], 8, 64);

        if (c < 8) {
            int kcol = w * 32 + ((c >> 2) & 1) * 16 + q * 4 + (c & 3);
            aggbf[((size_t)b * NELEC + i) * 128 + kcol] = f2bf(x);
        }
    }
}

extern "C" void kernel_launch(void* const* d_in, const int* in_sizes, int n_in,
                              void* d_out, int out_size, void* d_ws, size_t ws_size,
                              hipStream_t stream) {
    const float* dists = (const float*)d_in[0];
    const float* emb_e = (const float*)d_in[1];
    const float* emb_n = (const float*)d_in[2];
    const float* kW1   = (const float*)d_in[3];
    const float* kb1   = (const float*)d_in[4];
    const float* kW2   = (const float*)d_in[5];
    const float* kb2   = (const float*)d_in[6];
    const float* eiW   = (const float*)d_in[7];
    const float* eoW1  = (const float*)d_in[8];
    const float* eob1  = (const float*)d_in[9];
    const float* eoW2  = (const float*)d_in[10];
    const float* eob2  = (const float*)d_in[11];

    float* xs = (float*)d_out;                                  // (256,64,128) f32
    unsigned short* zsbf  = (unsigned short*)d_ws;              // (256,80,128) bf16
    unsigned short* aggbf = zsbf + NBS * NPART * KD;            // (256,64,128) bf16
    unsigned short* zs0   = aggbf + NBS * NELEC * KD;           // (80,128) bf16
    unsigned short* kW1Tf = zs0 + NPART * KD;                   // 3*4096
    unsigned short* kW2Tf = kW1Tf + 3 * 4096;                   // 3*16384
    unsigned short* Wf    = kW2Tf + 3 * 16384;                  // 9*16384
    float* kb1f = (float*)(Wf + 9 * 16384);                     // 6144 f32
    float* kb2f = kb1f + 3 * 4 * 64 * 8;                        // 6144 f32

    k_setup<<<11120, 256, 0, stream>>>(emb_e, emb_n, kW1, kW2, eiW, eoW1, eoW2,
                                       kb1, kb2, xs, zsbf, zs0,
                                       kW1Tf, kW2Tf, Wf, kb1f, kb2f);

    for (int l = 0; l < 3; ++l) {
        k_cfconv_mfma<<<NBS * (NELEC / IB), 256, 0, stream>>>(
            dists, kb1f, kb2f,
            l == 0 ? zs0 : zsbf, l == 0 ? 0 : NPART * KD,
            kW1Tf, kW2Tf, aggbf, l);

        if (l < 2) {
            k_tail<0><<<NBS * 2, 256, 0, stream>>>(
                aggbf,
                Wf + (size_t)(1 * 3 + l) * 16384, eob1 + l * DD,
                Wf + (size_t)(2 * 3 + l) * 16384, eob2 + l * DD,
                Wf + (size_t)(0 * 3 + (l + 1)) * 16384,
                xs, zsbf);
        } else {
            k_tail<1><<<NBS * 2, 256, 0, stream>>>(
                aggbf,
                Wf + (size_t)(1 * 3 + l) * 16384, eob1 + l * DD,
                Wf + (size_t)(2 * 3 + l) * 16384, eob2 + l * DD,
                nullptr,
                xs, zsbf);
        }
    }
}